// Round 13
// baseline (135.617 us; speedup 1.0000x reference)
//
#include <hip/hip_runtime.h>

// BNMorph forward — R13: zero-barrier, wave-independent fused kernel.
// Each 64-lane wave owns an 8-row strip: stages its own halos, finds its own
// candidates (dilation filter restored), resolves matches, splats, stores.
// No __syncthreads anywhere. 64x16 tile per block (2 waves), grid (16,20,8).
// B=8, H=320, W=1024. Outputs (concat, f32, each [B,H,W]):
//   0 morphedx, 1 morphedy, 2 orgpts_x, 3 orgpts_y, 4 correspts_x, 5 correspts_y

#define BB 8
#define HH 320
#define WW 1024
#define N_PIX (BB*HH*WW)            // 2,621,440
#define WPI (HH*(WW/32))            // 10240 words per image
#define RR 20
#define TLW 64
#define TLH 16
#define TXN (WW/TLW)                // 16
#define TYN (HH/TLH)                // 20
#define NQ 105
#define CAP 128                     // per-wave candidate capacity (mean ~78, +5.7σ)
#define NCRW 48                     // candidate rows per wave strip (8+2*20)
#define NSRW 50                     // src rows per wave (wy0-22 .. wy0+27)
#define NDRW 54                     // dst rows per wave (wy0-23 .. wy0+30)
#define WSTRIDE 53                  // odd stride
#define WTABN 2228                  // 42*53 = 2226, padded to x4
#define WTAB_OFF (2*BB*WPI*4)       // 655360 (16B aligned)

typedef unsigned long long u64;
typedef float v2f __attribute__((ext_vector_type(2)));

// ---- kernel 1: pack maps to bitmasks + build stride-53 weight table ----
__global__ __launch_bounds__(256) void pack_zero(
    const float* __restrict__ src, const float* __restrict__ dst,
    unsigned* __restrict__ packed, float* __restrict__ wtab_g)
{
    int t = threadIdx.x;
    int i = blockIdx.x * 256 + t;           // float4 index in [0, 2*N_PIX/4)
    if (i < WTABN) {
        int row = i / WSTRIDE, c = i - row * WSTRIDE;
        float v = 0.0f;
        if (row <= 40 && c >= 4 && c <= 44) {
            int dxv = c - 24, dyv = row - 20;
            float d = sqrtf((float)(dxv * dxv + dyv * dyv));
            v = 0.7f * expf((-d * 1.9f) / 24.0f);
        }
        wtab_g[i] = v;
    }
    const float4* p = (i < (N_PIX >> 2)) ? (const float4*)src + i
                                         : (const float4*)dst + (i - (N_PIX >> 2));
    float4 v = *p;
    unsigned nib = (v.x > 0.5f ? 1u : 0u) | (v.y > 0.5f ? 2u : 0u)
                 | (v.z > 0.5f ? 4u : 0u) | (v.w > 0.5f ? 8u : 0u);
    unsigned val = nib << ((t & 7) * 4);
    val |= __shfl_xor(val, 1);
    val |= __shfl_xor(val, 2);
    val |= __shfl_xor(val, 4);
    if ((t & 7) == 0) packed[i >> 3] = val;
}

// ---- kernel 2: zero-barrier fused kernel ----
__global__ __launch_bounds__(128, 4) void fused_morph(
    const unsigned* __restrict__ packed,
    const float* __restrict__ xx, const float* __restrict__ yy,
    const float* __restrict__ wtab_g,
    float* __restrict__ out)
{
    __shared__ __align__(16) float wtab[WTABN];          // 8.9 KB, shared (dup-written)
    __shared__ unsigned sSrc[2][NSRW][6];                // per-wave, pads at word 0,5
    __shared__ unsigned sDst[2][NDRW][6];
    __shared__ __align__(16) unsigned sPt[2][CAP + 8];
    __shared__ int prank[2][NQ];
    __shared__ unsigned char sVB[2][8 * TLW];            // strip rows only
    __shared__ int lcnt[2];

    int t = threadIdx.x;
    int lane = t & 63;
    int w = __builtin_amdgcn_readfirstlane(t >> 6);      // wave id 0/1
    int txT = blockIdx.x, tyT = blockIdx.y, b = blockIdx.z;
    int tx0 = txT * TLW, ty0 = tyT * TLH;
    int wy0 = ty0 + w * 8;                               // this wave's strip top
    int wb0 = (tx0 >> 5) - 1;
    const unsigned* psrc = packed + (size_t)b * WPI;
    const unsigned* pdst = packed + (size_t)(BB + b) * WPI;

    // stage weight table (both waves duplicate-write identical values)
    for (int i = lane; i < WTABN / 4; i += 64)
        ((float4*)wtab)[i] = ((const float4*)wtab_g)[i];
    // stage this wave's halos
    for (int i = lane; i < NSRW * 4; i += 64) {
        int r = i >> 2, wd = (i & 3) + 1;
        int gy = wy0 - 22 + r, gw = wb0 + (wd - 1);
        sSrc[w][r][wd] = (gy >= 0 && gy < HH && gw >= 0 && gw < 32) ? psrc[(gy << 5) + gw] : 0u;
    }
    for (int i = lane; i < NDRW * 4; i += 64) {
        int r = i >> 2, wd = (i & 3) + 1;
        int gy = wy0 - 23 + r, gw = wb0 + (wd - 1);
        sDst[w][r][wd] = (gy >= 0 && gy < HH && gw >= 0 && gw < 32) ? pdst[(gy << 5) + gw] : 0u;
    }
    if (lane < NDRW) { sDst[w][lane][0] = 0; sDst[w][lane][5] = 0; }
    if (lane < NSRW) { sSrc[w][lane][0] = 0; sSrc[w][lane][5] = 0; }
    for (int i = lane; i < NQ; i += 64) {
        int dx = (int)xx[i], dy = (int)yy[i];
        prank[w][(dy + 3) * 15 + (dx + 7)] = (i << 8) | ((dx + 7) << 4) | (dy + 3);
    }
    ((unsigned*)sVB[w])[lane] = 0; ((unsigned*)sVB[w])[lane + 64] = 0;
    if (lane == 0) lcnt[w] = 0;
    __builtin_amdgcn_wave_barrier();     // scheduling fence only (no HW cost)

    // Phase A: bit-parallel kept+found (dilation) over NCRW rows x 4 words
    for (int task = lane; task < NCRW * 4; task += 64) {
        int cr = task >> 2, wd = (task & 3) + 1;
        unsigned C = sSrc[w][cr + 2][wd];
        unsigned found = 0;
        if (C) {
            #define EXT5(row) ( (u64)((row)[wd-1] >> 30) \
                              | ((u64)(row)[wd] << 2) \
                              | ((u64)((row)[wd+1] & 3u) << 34) )
            u64 a = EXT5(sSrc[w][cr]) | EXT5(sSrc[w][cr + 1]);
            u64 or5 = a | (a >> 1) | (a >> 2) | (a >> 3) | (a >> 4);
            u64 e2 = EXT5(sSrc[w][cr + 2]);
            unsigned kept = C & ~(unsigned)(or5 | e2 | (e2 >> 1));
            if (kept) {
                u64 dil = 0;
                #pragma unroll
                for (int rr = 0; rr < 7; ++rr) {
                    const unsigned* row = sDst[w][cr + rr];
                    dil |= (u64)(row[wd-1] >> 25) | ((u64)row[wd] << 7)
                         | ((u64)(row[wd+1] & 0x7Fu) << 39);
                }
                u64 a2 = dil | (dil >> 1);
                u64 b2 = a2 | (a2 >> 2);
                u64 c2 = b2 | (b2 >> 4);
                u64 o15 = c2 | (c2 >> 7);
                found = kept & (unsigned)o15;
            }
        }
        if (wd == 1) found &= 0xFFFFF000u;    // px >= tx0-20
        if (wd == 4) found &= 0x000FFFFFu;    // px <= tx0+83
        if (found) {
            int nf = __popc(found);
            int base = atomicAdd(&lcnt[w], nf);
            unsigned fi = found;
            while (fi) {
                int bit = __builtin_ctz(fi); fi &= fi - 1;
                int px = tx0 - 32 + ((wd - 1) << 5) + bit;
                if (base < CAP) sPt[w][base] = (unsigned)((cr << 10) | px);
                ++base;
            }
        }
    }
    __builtin_amdgcn_wave_barrier();

    int nPts = lcnt[w]; if (nPts > CAP) nPts = CAP;

    // Phase B: per-candidate nearest-correspondence + record packing
    for (int i = lane; i < nPts; i += 64) {
        unsigned e = sPt[w][i];
        int cr = (int)(e >> 10), px = (int)(e & 1023u);
        int q = px - tx0 + 25;               // bit (px-7) rel. to LDS word0
        int widx = 1 + (q >> 5), sh = q & 31;
        u64 lo = 0, hi = 0;
        #pragma unroll
        for (int rr = 0; rr < 7; ++rr) {
            const unsigned* row = sDst[w][cr + rr];
            u64 win = (((u64)row[widx] | ((u64)row[widx + 1] << 32)) >> sh) & 0x7FFFull;
            if (rr < 4) lo |= win << (15 * rr);
            else        hi |= win << (15 * (rr - 4));
        }
        int minv = 0x7FFFFFFF;
        while (lo) { int bb2 = __builtin_ctzll(lo); lo &= lo - 1; int rv = prank[w][bb2];      if (rv < minv) minv = rv; }
        while (hi) { int bb2 = __builtin_ctzll(hi); hi &= hi - 1; int rv = prank[w][60 + bb2]; if (rv < minv) minv = rv; }
        int vxp7 = (minv >> 4) & 15, vyp3 = minv & 15;
        int py = wy0 - 20 + cr;
        sPt[w][i] = (unsigned)px | ((unsigned)py << 10)
                  | ((unsigned)vxp7 << 19) | ((unsigned)vyp3 << 23);
        if (px >= tx0 && px < tx0 + TLW && cr >= 20 && cr < 28)
            sVB[w][(cr - 20) * TLW + (px - tx0)] =
                (unsigned char)(0x80 | vxp7 | (vyp3 << 4));
    }
    int c4 = (nPts + 3) & ~3;
    if (lane < c4 - nPts) sPt[w][nPts + lane] = 0xFFFFFFFFu;   // py=511 sentinel
    __builtin_amdgcn_wave_barrier();

    // Phase C: branchless gather-splat over this wave's candidate list.
    // Thread = 4 cols x 2 rows, rows interleaved (wy0+g, wy0+g+4), g=lane>>4.
    int x0q = tx0 + (lane & 15) * 4;
    int yg  = wy0 + (lane >> 4);             // rows yg, yg+4

    v2f a0p[2][2] = {};          // a0 col-pairs: [ry][0]=(c0,c1) [ry][1]=(c2,c3)
    v2f av[2][4]  = {};          // (a1,a2) per [ry][col]

    for (int p = 0; p < c4; p += 4) {
        uint4 P = *(const uint4*)&sPt[w][p];
        #pragma unroll
        for (int k = 0; k < 4; ++k) {
            int spk = __builtin_amdgcn_readfirstlane(
                (int)(k == 0 ? P.x : k == 1 ? P.y : k == 2 ? P.z : P.w));
            int pxp21 = (spk & 1023) + 21;
            int pyp20 = ((spk >> 10) & 511) + 20;
            float pvx = (float)(((spk >> 19) & 15) - 7);
            float pvy = (float)(((spk >> 23) & 7) - 3);
            v2f vv = {pvx, pvy};

            int coff = pxp21 - x0q;                      // col3's table col
            coff = coff < 0 ? 0 : (coff > 45 ? 45 : coff);
            int d0r = pyp20 - yg;
            #pragma unroll
            for (int ry = 0; ry < 2; ++ry) {
                int dyr = d0r - 4 * ry;
                int rowi = ((unsigned)dyr > 40u) ? 41 : dyr;  // row 41 = zeros
                const float* wr = &wtab[rowi * WSTRIDE + coff];
                float w3 = wr[0], w2 = wr[1], w1 = wr[2], w0 = wr[3];
                a0p[ry][0] += (v2f){w0, w1};
                a0p[ry][1] += (v2f){w2, w3};
                av[ry][0] += w0 * vv;
                av[ry][1] += w1 * vv;
                av[ry][2] += w2 * vv;
                av[ry][3] += w3 * vv;
            }
        }
    }

    // Epilogue: all 6 planes, branchless, fully coalesced float4
    size_t bbase = (size_t)b * HH * WW;
    int lx = x0q - tx0;
    #pragma unroll
    for (int ry = 0; ry < 2; ++ry) {
        int y = yg + 4 * ry;
        unsigned vb4 = *(const unsigned*)&sVB[w][(y - wy0) * TLW + lx];
        size_t idx = bbase + (size_t)y * WW + x0q;
        float d0 = a0p[ry][0].x + 1.6f, d1 = a0p[ry][0].y + 1.6f;
        float d2 = a0p[ry][1].x + 1.6f, d3 = a0p[ry][1].y + 1.6f;
        float4 ox = { (float)x0q     + av[ry][0].x / d0, (float)(x0q+1) + av[ry][1].x / d1,
                      (float)(x0q+2) + av[ry][2].x / d2, (float)(x0q+3) + av[ry][3].x / d3 };
        float4 oy = { (float)y + av[ry][0].y / d0, (float)y + av[ry][1].y / d1,
                      (float)y + av[ry][2].y / d2, (float)y + av[ry][3].y / d3 };
        float4 o2, o3, o4, o5;
        float* po2 = &o2.x; float* po3 = &o3.x; float* po4 = &o4.x; float* po5 = &o5.x;
        #pragma unroll
        for (int jj = 0; jj < 4; ++jj) {
            unsigned by = (vb4 >> (8 * jj)) & 255u;
            float fm  = (float)(by >> 7);
            float fvx = (float)((int)(by & 15u) - 7);
            float fvy = (float)((int)((by >> 4) & 7u) - 3);
            float fx  = (float)(x0q + jj);
            po2[jj] = fx * fm;
            po3[jj] = (float)y * fm;
            po4[jj] = (fx + fvx) * fm;
            po5[jj] = ((float)y + fvy) * fm;
        }
        *reinterpret_cast<float4*>(out + idx)                     = ox;
        *reinterpret_cast<float4*>(out + (size_t)N_PIX + idx)     = oy;
        *reinterpret_cast<float4*>(out + 2 * (size_t)N_PIX + idx) = o2;
        *reinterpret_cast<float4*>(out + 3 * (size_t)N_PIX + idx) = o3;
        *reinterpret_cast<float4*>(out + 4 * (size_t)N_PIX + idx) = o4;
        *reinterpret_cast<float4*>(out + 5 * (size_t)N_PIX + idx) = o5;
    }
}

extern "C" void kernel_launch(void* const* d_in, const int* in_sizes, int n_in,
                              void* d_out, int out_size, void* d_ws, size_t ws_size,
                              hipStream_t stream) {
    const float* src = (const float*)d_in[0];
    const float* dst = (const float*)d_in[1];
    const float* xx  = (const float*)d_in[2];
    const float* yy  = (const float*)d_in[3];
    float* out = (float*)d_out;

    unsigned* packed = (unsigned*)d_ws;
    float*    wtab_g = (float*)((char*)d_ws + WTAB_OFF);

    pack_zero<<<(2 * N_PIX / 4) / 256, 256, 0, stream>>>(src, dst, packed, wtab_g);

    dim3 g2(TXN, TYN, BB);
    fused_morph<<<g2, 128, 0, stream>>>(packed, xx, yy, wtab_g, out);
}

// Round 14
// 127.343 us; speedup vs baseline: 1.0650x; 1.0650x over previous
//
#include <hip/hip_runtime.h>

// BNMorph forward — R14: R11 structure exactly, with LDS diet for occupancy.
// 64x16 tiles, 128-thread blocks, stride-49 table, interleaved y-groups,
// sWav aliased over dead halo storage. ~13.3 KB LDS -> 12 blocks/CU.
// B=8, H=320, W=1024. Outputs (concat, f32, each [B,H,W]):
//   0 morphedx, 1 morphedy, 2 orgpts_x, 3 orgpts_y, 4 correspts_x, 5 correspts_y

#define BB 8
#define HH 320
#define WW 1024
#define N_PIX (BB*HH*WW)            // 2,621,440
#define WPI (HH*(WW/32))            // 10240 words per image
#define RR 20
#define TLW 64
#define TLH 16
#define TXN (WW/TLW)                // 16
#define TYN (HH/TLH)                // 20
#define NQ 105
#define CAP 160                     // per-tile candidate capacity (mean ~82)
#define NCR (TLH+40)                // 56 candidate rows
#define NSR (NCR+2)                 // 58 src rows
#define NDR (NCR+6)                 // 62 dst rows
#define WSTRIDE 49                  // odd stride; data cols 4..44, zeros 0..3,45..48
#define WTABN 2060                  // 42*49 = 2058, padded to x4
#define WTAB_OFF (2*BB*WPI*4)       // 655360 (16B aligned)

// sMem byte offsets (all 16B aligned)
#define O_WTAB  0                   // float[2060]               -> 8240
#define O_SRC   8240                // unsigned[58][6]           -> 9632
#define O_DST   9632                // unsigned[62][6]           -> 11120
#define O_WAV   8240                // alias: 2 x 164 u32 (dead halos)
#define O_SPT   11120               // unsigned[168]             -> 11792
#define O_PRANK 11792               // int[105] -> 12212, pad    -> 12224
#define O_SVB   12224               // uchar[1024]               -> 13248
#define O_LCNT  13248               // int                       -> 13264
#define SMEM_BYTES 13264

typedef unsigned long long u64;
typedef float v2f __attribute__((ext_vector_type(2)));

// ---- kernel 1: pack maps to bitmasks + build stride-49 weight table ----
__global__ __launch_bounds__(256) void pack_zero(
    const float* __restrict__ src, const float* __restrict__ dst,
    unsigned* __restrict__ packed, float* __restrict__ wtab_g)
{
    int t = threadIdx.x;
    int i = blockIdx.x * 256 + t;           // float4 index in [0, 2*N_PIX/4)
    if (i < WTABN) {
        int row = i / WSTRIDE, c = i - row * WSTRIDE;
        float v = 0.0f;
        if (row <= 40 && c >= 4 && c <= 44) {
            int dxv = c - 24, dyv = row - 20;
            float d = sqrtf((float)(dxv * dxv + dyv * dyv));
            v = 0.7f * expf((-d * 1.9f) / 24.0f);
        }
        wtab_g[i] = v;
    }
    const float4* p = (i < (N_PIX >> 2)) ? (const float4*)src + i
                                         : (const float4*)dst + (i - (N_PIX >> 2));
    float4 v = *p;
    unsigned nib = (v.x > 0.5f ? 1u : 0u) | (v.y > 0.5f ? 2u : 0u)
                 | (v.z > 0.5f ? 4u : 0u) | (v.w > 0.5f ? 8u : 0u);
    unsigned val = nib << ((t & 7) * 4);
    val |= __shfl_xor(val, 1);
    val |= __shfl_xor(val, 2);
    val |= __shfl_xor(val, 4);
    if ((t & 7) == 0) packed[i >> 3] = val;
}

// ---- kernel 2: fused point-finding + wave-compacted splat, 64x16 tiles ----
// 128 threads (2 waves), grid (16, 20, 8) = 2560 blocks.
__global__ __launch_bounds__(128, 6) void fused_morph(
    const unsigned* __restrict__ packed,
    const float* __restrict__ xx, const float* __restrict__ yy,
    const float* __restrict__ wtab_g,
    float* __restrict__ out)
{
    __shared__ __align__(16) unsigned char sMem[SMEM_BYTES];
    float* wtab = (float*)(sMem + O_WTAB);
    unsigned (*sSrc)[6] = (unsigned(*)[6])(sMem + O_SRC);
    unsigned (*sDst)[6] = (unsigned(*)[6])(sMem + O_DST);
    unsigned* sPt = (unsigned*)(sMem + O_SPT);
    int* prank = (int*)(sMem + O_PRANK);
    unsigned char* sVB = sMem + O_SVB;
    int* lcnt = (int*)(sMem + O_LCNT);

    int t = threadIdx.x;
    int txT = blockIdx.x, tyT = blockIdx.y, b = blockIdx.z;
    int tx0 = txT * TLW, ty0 = tyT * TLH;
    int wb0 = (tx0 >> 5) - 1;
    const unsigned* psrc = packed + (size_t)b * WPI;
    const unsigned* pdst = packed + (size_t)(BB + b) * WPI;

    // stage weight table (515 float4)
    for (int i = t; i < WTABN / 4; i += 128)
        ((float4*)wtab)[i] = ((const float4*)wtab_g)[i];
    // stage bitmask halos
    for (int i = t; i < NSR * 4; i += 128) {
        int r = i >> 2, w = (i & 3) + 1;
        int gy = ty0 - 22 + r, gw = wb0 + (w - 1);
        sSrc[r][w] = (gy >= 0 && gy < HH && gw >= 0 && gw < 32) ? psrc[(gy << 5) + gw] : 0u;
    }
    for (int i = t; i < NDR * 4; i += 128) {
        int r = i >> 2, w = (i & 3) + 1;
        int gy = ty0 - 23 + r, gw = wb0 + (w - 1);
        sDst[r][w] = (gy >= 0 && gy < HH && gw >= 0 && gw < 32) ? pdst[(gy << 5) + gw] : 0u;
    }
    if (t < NDR) { sDst[t][0] = 0; sDst[t][5] = 0; if (t < NSR) { sSrc[t][0] = 0; sSrc[t][5] = 0; } }
    if (t < NQ) {
        int dx = (int)xx[t], dy = (int)yy[t];
        prank[(dy + 3) * 15 + (dx + 7)] = (t << 8) | ((dx + 7) << 4) | (dy + 3);
    }
    ((unsigned*)sVB)[t] = 0; ((unsigned*)sVB)[t + 128] = 0;
    if (t == 0) lcnt[0] = 0;
    __syncthreads();

    // Phase A: bit-parallel kept+found (dilation) over NCR rows x 4 words
    for (int task = t; task < NCR * 4; task += 128) {
        int cr = task >> 2, w = (task & 3) + 1;
        unsigned C = sSrc[cr + 2][w];
        unsigned found = 0;
        if (C) {
            #define EXT5(row) ( (u64)((row)[w-1] >> 30) \
                              | ((u64)(row)[w] << 2) \
                              | ((u64)((row)[w+1] & 3u) << 34) )
            u64 a = EXT5(sSrc[cr]) | EXT5(sSrc[cr + 1]);
            u64 or5 = a | (a >> 1) | (a >> 2) | (a >> 3) | (a >> 4);
            u64 e2 = EXT5(sSrc[cr + 2]);
            unsigned kept = C & ~(unsigned)(or5 | e2 | (e2 >> 1));
            if (kept) {
                u64 dil = 0;
                #pragma unroll
                for (int rr = 0; rr < 7; ++rr) {
                    const unsigned* row = sDst[cr + rr];
                    dil |= (u64)(row[w-1] >> 25) | ((u64)row[w] << 7)
                         | ((u64)(row[w+1] & 0x7Fu) << 39);
                }
                u64 a2 = dil | (dil >> 1);
                u64 b2 = a2 | (a2 >> 2);
                u64 c2 = b2 | (b2 >> 4);
                u64 o15 = c2 | (c2 >> 7);
                found = kept & (unsigned)o15;
            }
        }
        if (w == 1) found &= 0xFFFFF000u;    // px >= tx0-20
        if (w == 4) found &= 0x000FFFFFu;    // px <= tx0+83
        if (found) {
            int nf = __popc(found);
            int base = atomicAdd(lcnt, nf);
            unsigned fi = found;
            while (fi) {
                int bit = __builtin_ctz(fi); fi &= fi - 1;
                int px = tx0 - 32 + ((w - 1) << 5) + bit;
                if (base < CAP) sPt[base] = (unsigned)((cr << 10) | px);
                ++base;
            }
        }
    }
    __syncthreads();
    int nPts = lcnt[0]; if (nPts > CAP) nPts = CAP;

    // Phase B: per-candidate nearest-correspondence + record packing
    for (int i = t; i < nPts; i += 128) {
        unsigned e = sPt[i];
        int cr = (int)(e >> 10), px = (int)(e & 1023u);
        int q = px - tx0 + 25;               // bit (px-7) rel. to LDS word0
        int widx = 1 + (q >> 5), sh = q & 31;
        u64 lo = 0, hi = 0;
        #pragma unroll
        for (int rr = 0; rr < 7; ++rr) {
            const unsigned* row = sDst[cr + rr];
            u64 win = (((u64)row[widx] | ((u64)row[widx + 1] << 32)) >> sh) & 0x7FFFull;
            if (rr < 4) lo |= win << (15 * rr);
            else        hi |= win << (15 * (rr - 4));
        }
        int minv = 0x7FFFFFFF;
        while (lo) { int bb2 = __builtin_ctzll(lo); lo &= lo - 1; int rv = prank[bb2];      if (rv < minv) minv = rv; }
        while (hi) { int bb2 = __builtin_ctzll(hi); hi &= hi - 1; int rv = prank[60 + bb2]; if (rv < minv) minv = rv; }
        int vxp7 = (minv >> 4) & 15, vyp3 = minv & 15;
        int py = ty0 - 20 + cr;
        sPt[i] = (unsigned)px | ((unsigned)py << 10)
               | ((unsigned)vxp7 << 19) | ((unsigned)vyp3 << 23);
        if (px >= tx0 && px < tx0 + TLW && cr >= 20 && cr < 20 + TLH)
            sVB[(cr - 20) * TLW + (px - tx0)] =
                (unsigned char)(0x80 | vxp7 | (vyp3 << 4));
    }
    __syncthreads();   // after this barrier the halo regions are dead -> sWav

    // Per-wave y-strip compaction into aliased region (wave-local)
    int lane = t & 63, w = __builtin_amdgcn_readfirstlane(t >> 6);
    unsigned* sWavW = (unsigned*)(sMem + O_WAV) + w * 164;
    int wy0 = ty0 + w * 8;                   // wave strip rows [wy0, wy0+7]
    int cw = 0;
    for (int base = 0; base < nPts; base += 64) {
        int i = base + lane;
        unsigned pk = (i < nPts) ? sPt[i] : 0xFFFFFFFFu;
        int py = (int)((pk >> 10) & 511u);
        bool pass = (i < nPts) & (py >= wy0 - 20) & (py <= wy0 + 27);
        u64 m = __ballot(pass);
        if (pass) {
            int idx = __popcll(m & ((1ull << lane) - 1ull));
            sWavW[cw + idx] = pk;
        }
        cw += __popcll(m);
    }
    int c4 = (cw + 3) & ~3;
    if (lane < c4 - cw) sWavW[cw + lane] = 0xFFFFFFFFu;   // py=511 sentinel

    // Phase C: branchless gather-splat. Thread = 4 cols x 2 rows, rows
    // interleaved (wy0+g, wy0+g+4), g = lane>>4.
    int x0q = tx0 + (lane & 15) * 4;
    int yg  = wy0 + (lane >> 4);             // rows yg, yg+4

    v2f a0p[2][2] = {};          // a0 col-pairs: [ry][0]=(c0,c1) [ry][1]=(c2,c3)
    v2f av[2][4]  = {};          // (a1,a2) per [ry][col]

    for (int p = 0; p < c4; p += 4) {
        uint4 P = *(const uint4*)&sWavW[p];
        #pragma unroll
        for (int k = 0; k < 4; ++k) {
            int spk = __builtin_amdgcn_readfirstlane(
                (int)(k == 0 ? P.x : k == 1 ? P.y : k == 2 ? P.z : P.w));
            int pxp21 = (spk & 1023) + 21;
            int pyp20 = ((spk >> 10) & 511) + 20;
            float pvx = (float)(((spk >> 19) & 15) - 7);
            float pvy = (float)(((spk >> 23) & 7) - 3);
            v2f vv = {pvx, pvy};

            int coff = pxp21 - x0q;                      // col3's table col
            coff = coff < 0 ? 0 : (coff > 45 ? 45 : coff);
            int d0r = pyp20 - yg;
            #pragma unroll
            for (int ry = 0; ry < 2; ++ry) {
                int dyr = d0r - 4 * ry;
                int rowi = ((unsigned)dyr > 40u) ? 41 : dyr;  // row 41 = zeros
                const float* wr = &wtab[rowi * WSTRIDE + coff];
                float w3 = wr[0], w2 = wr[1], w1 = wr[2], w0 = wr[3];
                a0p[ry][0] += (v2f){w0, w1};
                a0p[ry][1] += (v2f){w2, w3};
                av[ry][0] += w0 * vv;
                av[ry][1] += w1 * vv;
                av[ry][2] += w2 * vv;
                av[ry][3] += w3 * vv;
            }
        }
    }

    // Epilogue: all 6 planes, branchless, fully coalesced float4
    size_t bbase = (size_t)b * HH * WW;
    int lx = x0q - tx0;
    #pragma unroll
    for (int ry = 0; ry < 2; ++ry) {
        int y = yg + 4 * ry;
        int ly = y - ty0;
        unsigned vb4 = *(const unsigned*)&sVB[ly * TLW + lx];
        size_t idx = bbase + (size_t)y * WW + x0q;
        float d0 = a0p[ry][0].x + 1.6f, d1 = a0p[ry][0].y + 1.6f;
        float d2 = a0p[ry][1].x + 1.6f, d3 = a0p[ry][1].y + 1.6f;
        float4 ox = { (float)x0q     + av[ry][0].x / d0, (float)(x0q+1) + av[ry][1].x / d1,
                      (float)(x0q+2) + av[ry][2].x / d2, (float)(x0q+3) + av[ry][3].x / d3 };
        float4 oy = { (float)y + av[ry][0].y / d0, (float)y + av[ry][1].y / d1,
                      (float)y + av[ry][2].y / d2, (float)y + av[ry][3].y / d3 };
        float4 o2, o3, o4, o5;
        float* po2 = &o2.x; float* po3 = &o3.x; float* po4 = &o4.x; float* po5 = &o5.x;
        #pragma unroll
        for (int jj = 0; jj < 4; ++jj) {
            unsigned by = (vb4 >> (8 * jj)) & 255u;
            float fm  = (float)(by >> 7);
            float fvx = (float)((int)(by & 15u) - 7);
            float fvy = (float)((int)((by >> 4) & 7u) - 3);
            float fx  = (float)(x0q + jj);
            po2[jj] = fx * fm;
            po3[jj] = (float)y * fm;
            po4[jj] = (fx + fvx) * fm;
            po5[jj] = ((float)y + fvy) * fm;
        }
        *reinterpret_cast<float4*>(out + idx)                     = ox;
        *reinterpret_cast<float4*>(out + (size_t)N_PIX + idx)     = oy;
        *reinterpret_cast<float4*>(out + 2 * (size_t)N_PIX + idx) = o2;
        *reinterpret_cast<float4*>(out + 3 * (size_t)N_PIX + idx) = o3;
        *reinterpret_cast<float4*>(out + 4 * (size_t)N_PIX + idx) = o4;
        *reinterpret_cast<float4*>(out + 5 * (size_t)N_PIX + idx) = o5;
    }
}

extern "C" void kernel_launch(void* const* d_in, const int* in_sizes, int n_in,
                              void* d_out, int out_size, void* d_ws, size_t ws_size,
                              hipStream_t stream) {
    const float* src = (const float*)d_in[0];
    const float* dst = (const float*)d_in[1];
    const float* xx  = (const float*)d_in[2];
    const float* yy  = (const float*)d_in[3];
    float* out = (float*)d_out;

    unsigned* packed = (unsigned*)d_ws;
    float*    wtab_g = (float*)((char*)d_ws + WTAB_OFF);

    pack_zero<<<(2 * N_PIX / 4) / 256, 256, 0, stream>>>(src, dst, packed, wtab_g);

    dim3 g2(TXN, TYN, BB);
    fused_morph<<<g2, 128, 0, stream>>>(packed, xx, yy, wtab_g, out);
}

// Round 15
// 126.336 us; speedup vs baseline: 1.0735x; 1.0080x over previous
//
#include <hip/hip_runtime.h>

// BNMorph forward — R15: 32x16 tiles (5120 blocks) for TLP; wave = 8-row strip
// of 32-wide tile, thread = 4 cols x 1 row; stride-53 table; sWav aliased.
// B=8, H=320, W=1024. Outputs (concat, f32, each [B,H,W]):
//   0 morphedx, 1 morphedy, 2 orgpts_x, 3 orgpts_y, 4 correspts_x, 5 correspts_y

#define BB 8
#define HH 320
#define WW 1024
#define N_PIX (BB*HH*WW)            // 2,621,440
#define WPI (HH*(WW/32))            // 10240 words per image
#define TLW 32
#define TLH 16
#define TXN (WW/TLW)                // 32
#define TYN (HH/TLH)                // 20
#define NQ 105
#define CAP 112                     // per-tile candidate capacity (mean ~45)
#define NCR (TLH+40)                // 56 candidate rows
#define NSR (NCR+2)                 // 58 src rows (ty0-22 .. ty0+35)
#define NDR (NCR+6)                 // 62 dst rows (ty0-23 .. ty0+38)
#define WSTRIDE 53                  // odd stride (R11-verified conflict class)
#define WTABN 2228                  // 42*53 = 2226, padded to x4
#define WTAB_OFF (2*BB*WPI*4)       // 655360 (16B aligned)

// sMem byte offsets (16B aligned where vector-read)
#define O_WTAB  0                   // float[2228]            -> 8912
#define O_SRC   8912                // unsigned[58][5]        -> 10072
#define O_WAV   8912                // alias: 2 x 120 u32 (sSrc dead by then)
#define O_DST   10072               // unsigned[62][5]        -> 11312
#define O_SPT   11312               // unsigned[120]          -> 11792
#define O_PRANK 11792               // int[105] -> 12212, pad -> 12224
#define O_SVB   12224               // uchar[512]             -> 12736
#define O_LCNT  12736               // int                    -> 12752
#define SMEM_BYTES 12752

typedef unsigned long long u64;
typedef float v2f __attribute__((ext_vector_type(2)));

// ---- kernel 1: pack maps to bitmasks + build stride-53 weight table ----
__global__ __launch_bounds__(256) void pack_zero(
    const float* __restrict__ src, const float* __restrict__ dst,
    unsigned* __restrict__ packed, float* __restrict__ wtab_g)
{
    int t = threadIdx.x;
    int i = blockIdx.x * 256 + t;           // float4 index in [0, 2*N_PIX/4)
    if (i < WTABN) {
        int row = i / WSTRIDE, c = i - row * WSTRIDE;
        float v = 0.0f;
        if (row <= 40 && c >= 4 && c <= 44) {
            int dxv = c - 24, dyv = row - 20;
            float d = sqrtf((float)(dxv * dxv + dyv * dyv));
            v = 0.7f * expf((-d * 1.9f) / 24.0f);
        }
        wtab_g[i] = v;
    }
    const float4* p = (i < (N_PIX >> 2)) ? (const float4*)src + i
                                         : (const float4*)dst + (i - (N_PIX >> 2));
    float4 v = *p;
    unsigned nib = (v.x > 0.5f ? 1u : 0u) | (v.y > 0.5f ? 2u : 0u)
                 | (v.z > 0.5f ? 4u : 0u) | (v.w > 0.5f ? 8u : 0u);
    unsigned val = nib << ((t & 7) * 4);
    val |= __shfl_xor(val, 1);
    val |= __shfl_xor(val, 2);
    val |= __shfl_xor(val, 4);
    if ((t & 7) == 0) packed[i >> 3] = val;
}

// ---- kernel 2: fused point-finding + splat, 32x16 tiles, grid (32,20,8) ----
// LDS word k (0..4) of a row = global word (tx0>>5) - 2 + k (OOB-zero).
// Candidate words are k = 1,2,3 (px in [tx0-20, tx0+51] after masks).
__global__ __launch_bounds__(128, 6) void fused_morph(
    const unsigned* __restrict__ packed,
    const float* __restrict__ xx, const float* __restrict__ yy,
    const float* __restrict__ wtab_g,
    float* __restrict__ out)
{
    __shared__ __align__(16) unsigned char sMem[SMEM_BYTES];
    float* wtab = (float*)(sMem + O_WTAB);
    unsigned (*sSrc)[5] = (unsigned(*)[5])(sMem + O_SRC);
    unsigned (*sDst)[5] = (unsigned(*)[5])(sMem + O_DST);
    unsigned* sPt = (unsigned*)(sMem + O_SPT);
    int* prank = (int*)(sMem + O_PRANK);
    unsigned char* sVB = sMem + O_SVB;
    int* lcnt = (int*)(sMem + O_LCNT);

    int t = threadIdx.x;
    int txT = blockIdx.x, tyT = blockIdx.y, b = blockIdx.z;
    int tx0 = txT * TLW, ty0 = tyT * TLH;
    const unsigned* psrc = packed + (size_t)b * WPI;
    const unsigned* pdst = packed + (size_t)(BB + b) * WPI;

    // stage weight table (557 float4)
    for (int i = t; i < WTABN / 4; i += 128)
        ((float4*)wtab)[i] = ((const float4*)wtab_g)[i];
    // stage bitmask halos: 5 words/row, global word txT-2+k
    for (int i = t; i < NSR * 5; i += 128) {
        int r = i / 5, k = i - r * 5;
        int gy = ty0 - 22 + r, gw = txT - 2 + k;
        sSrc[r][k] = (gy >= 0 && gy < HH && gw >= 0 && gw < 32) ? psrc[(gy << 5) + gw] : 0u;
    }
    for (int i = t; i < NDR * 5; i += 128) {
        int r = i / 5, k = i - r * 5;
        int gy = ty0 - 23 + r, gw = txT - 2 + k;
        sDst[r][k] = (gy >= 0 && gy < HH && gw >= 0 && gw < 32) ? pdst[(gy << 5) + gw] : 0u;
    }
    if (t < NQ) {
        int dx = (int)xx[t], dy = (int)yy[t];
        prank[(dy + 3) * 15 + (dx + 7)] = (t << 8) | ((dx + 7) << 4) | (dy + 3);
    }
    ((unsigned*)sVB)[t] = 0;                 // 512 B = 128 u32
    if (t == 0) lcnt[0] = 0;
    __syncthreads();

    // Phase A: bit-parallel kept+found over 56 rows x 3 candidate words
    for (int task = t; task < NCR * 3; task += 128) {
        int cr = task / 3, wd = task - cr * 3 + 1;   // wd in 1..3
        unsigned C = sSrc[cr + 2][wd];
        unsigned found = 0;
        if (C) {
            #define EXT5(row) ( (u64)((row)[wd-1] >> 30) \
                              | ((u64)(row)[wd] << 2) \
                              | ((u64)((row)[wd+1] & 3u) << 34) )
            u64 a = EXT5(sSrc[cr]) | EXT5(sSrc[cr + 1]);
            u64 or5 = a | (a >> 1) | (a >> 2) | (a >> 3) | (a >> 4);
            u64 e2 = EXT5(sSrc[cr + 2]);
            unsigned kept = C & ~(unsigned)(or5 | e2 | (e2 >> 1));
            if (kept) {
                u64 dil = 0;
                #pragma unroll
                for (int rr = 0; rr < 7; ++rr) {
                    const unsigned* row = sDst[cr + rr];
                    dil |= (u64)(row[wd-1] >> 25) | ((u64)row[wd] << 7)
                         | ((u64)(row[wd+1] & 0x7Fu) << 39);
                }
                u64 a2 = dil | (dil >> 1);
                u64 b2 = a2 | (a2 >> 2);
                u64 c2 = b2 | (b2 >> 4);
                u64 o15 = c2 | (c2 >> 7);
                found = kept & (unsigned)o15;
            }
        }
        if (wd == 1) found &= 0xFFFFF000u;    // px >= tx0-20
        if (wd == 3) found &= 0x000FFFFFu;    // px <= tx0+51
        if (found) {
            int nf = __popc(found);
            int base = atomicAdd(lcnt, nf);
            unsigned fi = found;
            while (fi) {
                int bit = __builtin_ctz(fi); fi &= fi - 1;
                int px = tx0 - 64 + (wd << 5) + bit;
                if (base < CAP) sPt[base] = (unsigned)((cr << 10) | px);
                ++base;
            }
        }
    }
    __syncthreads();
    int nPts = lcnt[0]; if (nPts > CAP) nPts = CAP;

    // Phase B: per-candidate nearest-correspondence + record packing
    for (int i = t; i < nPts; i += 128) {
        unsigned e = sPt[i];
        int cr = (int)(e >> 10), px = (int)(e & 1023u);
        int q = px - tx0 + 57;               // bit (px-7) rel. to LDS word0
        int widx = q >> 5, sh = q & 31;      // widx in 1..3
        u64 lo = 0, hi = 0;
        #pragma unroll
        for (int rr = 0; rr < 7; ++rr) {
            const unsigned* row = sDst[cr + rr];
            u64 win = (((u64)row[widx] | ((u64)row[widx + 1] << 32)) >> sh) & 0x7FFFull;
            if (rr < 4) lo |= win << (15 * rr);
            else        hi |= win << (15 * (rr - 4));
        }
        int minv = 0x7FFFFFFF;
        while (lo) { int bb2 = __builtin_ctzll(lo); lo &= lo - 1; int rv = prank[bb2];      if (rv < minv) minv = rv; }
        while (hi) { int bb2 = __builtin_ctzll(hi); hi &= hi - 1; int rv = prank[60 + bb2]; if (rv < minv) minv = rv; }
        int vxp7 = (minv >> 4) & 15, vyp3 = minv & 15;
        int py = ty0 - 20 + cr;
        sPt[i] = (unsigned)px | ((unsigned)py << 10)
               | ((unsigned)vxp7 << 19) | ((unsigned)vyp3 << 23);
        if (px >= tx0 && px < tx0 + TLW && cr >= 20 && cr < 20 + TLH)
            sVB[(cr - 20) * TLW + (px - tx0)] =
                (unsigned char)(0x80 | vxp7 | (vyp3 << 4));
    }
    __syncthreads();   // sSrc dead beyond this point -> sWav alias safe

    // Per-wave y-strip compaction into aliased region (wave-local)
    int lane = t & 63, w = __builtin_amdgcn_readfirstlane(t >> 6);
    unsigned* sWavW = (unsigned*)(sMem + O_WAV) + w * 120;
    int wy0 = ty0 + w * 8;                   // wave strip rows [wy0, wy0+7]
    int cw = 0;
    for (int base = 0; base < nPts; base += 64) {
        int i = base + lane;
        unsigned pk = (i < nPts) ? sPt[i] : 0xFFFFFFFFu;
        int py = (int)((pk >> 10) & 511u);
        bool pass = (i < nPts) & (py >= wy0 - 20) & (py <= wy0 + 27);
        u64 m = __ballot(pass);
        if (pass) {
            int idx = __popcll(m & ((1ull << lane) - 1ull));
            sWavW[cw + idx] = pk;
        }
        cw += __popcll(m);
    }
    int c4 = (cw + 3) & ~3;
    if (lane < c4 - cw) sWavW[cw + lane] = 0xFFFFFFFFu;   // py=511 sentinel

    // Phase C: branchless gather-splat. Thread = 4 cols x 1 row:
    // xg = lane&7 (8 x-groups x 4 cols = 32), row = lane>>3 (8 rows).
    int x0q = tx0 + (lane & 7) * 4;
    int y   = wy0 + (lane >> 3);

    v2f a0p0 = {}, a0p1 = {};    // a0 col-pairs (c0,c1), (c2,c3)
    v2f av[4] = {};              // (a1,a2) per col

    for (int p = 0; p < c4; p += 4) {
        uint4 P = *(const uint4*)&sWavW[p];
        #pragma unroll
        for (int k = 0; k < 4; ++k) {
            int spk = __builtin_amdgcn_readfirstlane(
                (int)(k == 0 ? P.x : k == 1 ? P.y : k == 2 ? P.z : P.w));
            int px = spk & 1023;
            int pyp20 = ((spk >> 10) & 511) + 20;
            float pvx = (float)(((spk >> 19) & 15) - 7);
            float pvy = (float)(((spk >> 23) & 7) - 3);
            v2f vv = {pvx, pvy};

            int coff = px + 21 - x0q;                    // col3's table col
            coff = coff < 0 ? 0 : (coff > 45 ? 45 : coff);
            int dyr = pyp20 - y;
            int rowi = ((unsigned)dyr > 40u) ? 41 : dyr; // row 41 = zeros
            const float* wr = &wtab[rowi * WSTRIDE + coff];
            float w3 = wr[0], w2 = wr[1], w1 = wr[2], w0 = wr[3];
            a0p0 += (v2f){w0, w1};
            a0p1 += (v2f){w2, w3};
            av[0] += w0 * vv;
            av[1] += w1 * vv;
            av[2] += w2 * vv;
            av[3] += w3 * vv;
        }
    }

    // Epilogue: all 6 planes, branchless, float4 per plane
    size_t bbase = (size_t)b * HH * WW;
    unsigned vb4 = *(const unsigned*)&sVB[(y - ty0) * TLW + (x0q - tx0)];
    size_t idx = bbase + (size_t)y * WW + x0q;
    float d0 = a0p0.x + 1.6f, d1 = a0p0.y + 1.6f;
    float d2 = a0p1.x + 1.6f, d3 = a0p1.y + 1.6f;
    float4 ox = { (float)x0q     + av[0].x / d0, (float)(x0q+1) + av[1].x / d1,
                  (float)(x0q+2) + av[2].x / d2, (float)(x0q+3) + av[3].x / d3 };
    float4 oy = { (float)y + av[0].y / d0, (float)y + av[1].y / d1,
                  (float)y + av[2].y / d2, (float)y + av[3].y / d3 };
    float4 o2, o3, o4, o5;
    float* po2 = &o2.x; float* po3 = &o3.x; float* po4 = &o4.x; float* po5 = &o5.x;
    #pragma unroll
    for (int jj = 0; jj < 4; ++jj) {
        unsigned by = (vb4 >> (8 * jj)) & 255u;
        float fm  = (float)(by >> 7);
        float fvx = (float)((int)(by & 15u) - 7);
        float fvy = (float)((int)((by >> 4) & 7u) - 3);
        float fx  = (float)(x0q + jj);
        po2[jj] = fx * fm;
        po3[jj] = (float)y * fm;
        po4[jj] = (fx + fvx) * fm;
        po5[jj] = ((float)y + fvy) * fm;
    }
    *reinterpret_cast<float4*>(out + idx)                     = ox;
    *reinterpret_cast<float4*>(out + (size_t)N_PIX + idx)     = oy;
    *reinterpret_cast<float4*>(out + 2 * (size_t)N_PIX + idx) = o2;
    *reinterpret_cast<float4*>(out + 3 * (size_t)N_PIX + idx) = o3;
    *reinterpret_cast<float4*>(out + 4 * (size_t)N_PIX + idx) = o4;
    *reinterpret_cast<float4*>(out + 5 * (size_t)N_PIX + idx) = o5;
}

extern "C" void kernel_launch(void* const* d_in, const int* in_sizes, int n_in,
                              void* d_out, int out_size, void* d_ws, size_t ws_size,
                              hipStream_t stream) {
    const float* src = (const float*)d_in[0];
    const float* dst = (const float*)d_in[1];
    const float* xx  = (const float*)d_in[2];
    const float* yy  = (const float*)d_in[3];
    float* out = (float*)d_out;

    unsigned* packed = (unsigned*)d_ws;
    float*    wtab_g = (float*)((char*)d_ws + WTAB_OFF);

    pack_zero<<<(2 * N_PIX / 4) / 256, 256, 0, stream>>>(src, dst, packed, wtab_g);

    dim3 g2(TXN, TYN, BB);
    fused_morph<<<g2, 128, 0, stream>>>(packed, xx, yy, wtab_g, out);
}